// Round 2
// baseline (385.847 us; speedup 1.0000x reference)
//
#include <hip/hip_runtime.h>

// ChannelLatentMixer: out[b, 0:64, :] = z[b]; out[b, 64:128, :] = per-channel mean.
// B=4096, C=32, row-block = 64*128 = 8192 floats.
#define NB      4096
#define NCH     32
#define ND      8192    // floats per z row-block
#define OUTROW  16384   // floats per output row-block
#define NCHUNK  8       // column chunks of 1024 floats (256 threads x float4)
#define NSEG    4       // row-list segments per (channel, chunk)

// ---- kernel 1: build per-channel row lists ---------------------------------
__global__ void build_lists_kernel(const int* __restrict__ ch,
                                   int* __restrict__ counts,
                                   int* __restrict__ lists) {
    int b = blockIdx.x * blockDim.x + threadIdx.x;
    if (b < NB) {
        int c = ch[b];
        int pos = atomicAdd(&counts[c], 1);
        lists[c * NB + pos] = b;
    }
}

// ---- kernel 2: copy z -> out z-half, accumulate partial channel sums -------
// grid = NCH * NCHUNK * NSEG blocks of 256 threads.
__global__ __launch_bounds__(256) void copy_sum_kernel(const float* __restrict__ z,
                                                       const int* __restrict__ counts,
                                                       const int* __restrict__ lists,
                                                       float* __restrict__ sums,
                                                       float* __restrict__ out) {
    const int bid   = blockIdx.x;
    const int c     = bid / (NCHUNK * NSEG);
    const int rem   = bid % (NCHUNK * NSEG);
    const int chunk = rem / NSEG;
    const int seg   = rem % NSEG;
    const int off   = chunk * 1024 + threadIdx.x * 4;   // float offset in row
    const int cnt   = counts[c];
    const int* __restrict__ lst = lists + c * NB;

    float4 acc = make_float4(0.f, 0.f, 0.f, 0.f);

    int i = seg;
    for (; i + 3 * NSEG < cnt; i += 4 * NSEG) {
        const int b0 = lst[i];
        const int b1 = lst[i + NSEG];
        const int b2 = lst[i + 2 * NSEG];
        const int b3 = lst[i + 3 * NSEG];
        const float4 v0 = *(const float4*)(z + b0 * ND + off);
        const float4 v1 = *(const float4*)(z + b1 * ND + off);
        const float4 v2 = *(const float4*)(z + b2 * ND + off);
        const float4 v3 = *(const float4*)(z + b3 * ND + off);
        *(float4*)(out + b0 * OUTROW + off) = v0;
        *(float4*)(out + b1 * OUTROW + off) = v1;
        *(float4*)(out + b2 * OUTROW + off) = v2;
        *(float4*)(out + b3 * OUTROW + off) = v3;
        acc.x += (v0.x + v1.x) + (v2.x + v3.x);
        acc.y += (v0.y + v1.y) + (v2.y + v3.y);
        acc.z += (v0.z + v1.z) + (v2.z + v3.z);
        acc.w += (v0.w + v1.w) + (v2.w + v3.w);
    }
    for (; i < cnt; i += NSEG) {
        const int b = lst[i];
        const float4 v = *(const float4*)(z + b * ND + off);
        *(float4*)(out + b * OUTROW + off) = v;
        acc.x += v.x; acc.y += v.y; acc.z += v.z; acc.w += v.w;
    }

    float* s = sums + c * ND + off;
    atomicAdd(s + 0, acc.x);
    atomicAdd(s + 1, acc.y);
    atomicAdd(s + 2, acc.z);
    atomicAdd(s + 3, acc.w);
}

// ---- kernel 3: broadcast mean to aggr-half ---------------------------------
// grid = NB blocks of 256 threads; block b writes out[b, 64:128, :].
__global__ __launch_bounds__(256) void broadcast_kernel(const int* __restrict__ ch,
                                                        const int* __restrict__ counts,
                                                        const float* __restrict__ sums,
                                                        float* __restrict__ out) {
    const int b   = blockIdx.x;
    const int c   = ch[b];
    const float inv = 1.0f / fmaxf((float)counts[c], 1.0f);
    const float* __restrict__ s = sums + c * ND;
    float* __restrict__ o = out + b * OUTROW + ND;

#pragma unroll
    for (int k = 0; k < NCHUNK; ++k) {
        const int off = k * 1024 + threadIdx.x * 4;
        float4 m = *(const float4*)(s + off);
        m.x *= inv; m.y *= inv; m.z *= inv; m.w *= inv;
        *(float4*)(o + off) = m;
    }
}

extern "C" void kernel_launch(void* const* d_in, const int* in_sizes, int n_in,
                              void* d_out, int out_size, void* d_ws, size_t ws_size,
                              hipStream_t stream) {
    const float* z  = (const float*)d_in[0];
    const int*   ch = (const int*)d_in[1];
    float*       out = (float*)d_out;

    // ws layout: [0,128) counts, [128, 128+1MB) sums, then lists (512 KB).
    int*   counts = (int*)d_ws;
    float* sums   = (float*)((char*)d_ws + 128);
    int*   lists  = (int*)((char*)d_ws + 128 + NCH * ND * sizeof(float));

    hipMemsetAsync(d_ws, 0, 128 + NCH * ND * sizeof(float), stream);
    build_lists_kernel<<<(NB + 255) / 256, 256, 0, stream>>>(ch, counts, lists);
    copy_sum_kernel<<<NCH * NCHUNK * NSEG, 256, 0, stream>>>(z, counts, lists, sums, out);
    broadcast_kernel<<<NB, 256, 0, stream>>>(ch, counts, sums, out);
}